// Round 6
// baseline (290.535 us; speedup 1.0000x reference)
//
#include <hip/hip_runtime.h>
#include <hip/hip_bf16.h>
#include <hip/hip_fp16.h>
#include <math.h>

#define B_   2
#define N_   2048
#define D_   1024
#define H_   16
#define TD_  3072
#define LOG2E 1.44269504088896340736f
#define SCALE_Q (0.125f * LOG2E)

typedef short  bf16x8 __attribute__((ext_vector_type(8)));
typedef _Float16 f16x8 __attribute__((ext_vector_type(8)));
typedef float  f32x4  __attribute__((ext_vector_type(4)));
typedef float  f32x16 __attribute__((ext_vector_type(16)));

#define MFMA16(a, b, c)   __builtin_amdgcn_mfma_f32_16x16x32_bf16(a, b, c, 0, 0, 0)
#define MFMA32B(a, b, c)  __builtin_amdgcn_mfma_f32_32x32x16_bf16(a, b, c, 0, 0, 0)
#define MFMA32H(a, b, c)  __builtin_amdgcn_mfma_f32_32x32x16_f16(a, b, c, 0, 0, 0)

__device__ __forceinline__ ushort f2bf(float f) {
    union { float f; unsigned u; } v; v.f = f;
    unsigned r = (v.u + 0x7fffu + ((v.u >> 16) & 1u)) >> 16;
    return (ushort)r;
}
__device__ __forceinline__ unsigned pkrtz(float a, float b) {
    typedef __fp16 h2 __attribute__((ext_vector_type(2)));
    union { h2 h; unsigned u; } c;
    c.h = __builtin_amdgcn_cvt_pkrtz(a, b);
    return c.u;
}
__device__ __forceinline__ void async16(const void* g, void* l) {
    __builtin_amdgcn_global_load_lds(
        (const __attribute__((address_space(1))) unsigned*)g,
        (__attribute__((address_space(3))) unsigned*)l, 16, 0, 0);
}

// ---------------------------------------------------------------------------
// Preprocess: bf16 casts of x/W_in/W_out; fused term table
// term[q][k] = mask ? -1e30 : (k<nctx ? alpha*log2(ppr_k) - 4 : -4)   (f32)
// ---------------------------------------------------------------------------
__global__ __launch_bounds__(256) void preprocess(
    const float* __restrict__ x, const float* __restrict__ W_in,
    const float* __restrict__ W_out, const float* __restrict__ ctx_ppr,
    const float* __restrict__ log_alpha, const int* __restrict__ n_ctx_p,
    const int* __restrict__ mask,
    ushort* __restrict__ xb, ushort* __restrict__ wib, ushort* __restrict__ wob,
    float* __restrict__ term)
{
    const int J0 = 1048576, J1 = 786432, J2 = 262144, JT = 1048576;
    int t = blockIdx.x * 256 + threadIdx.x;
    if (t < J0 + J1 + J2) {
        const float* src; ushort* dst; int i = t;
        if (i < J0)           { src = x;      dst = xb;  }
        else if (i < J0 + J1) { i -= J0;      src = W_in;  dst = wib; }
        else                  { i -= J0 + J1; src = W_out; dst = wob; }
        float4 v = ((const float4*)src)[i];
        ushort4 o;
        o.x = f2bf(v.x); o.y = f2bf(v.y); o.z = f2bf(v.z); o.w = f2bf(v.w);
        ((ushort4*)dst)[i] = o;
    } else if (t < J0 + J1 + J2 + JT) {
        int i = t - (J0 + J1 + J2);          // one float4 of term, int4 of mask
        int k4 = (i & 511) * 4;
        int4 m = ((const int4*)mask)[i];
        int nc = n_ctx_p[0];
        float al = log_alpha[0];
        float4 o;
        float bv[4];
        #pragma unroll
        for (int j = 0; j < 4; ++j) {
            int k = k4 + j;
            bv[j] = (k < nc) ? (al * __log2f(fmaxf(ctx_ppr[k], 1e-8f)) - 4.f) : -4.f;
        }
        o.x = m.x ? -1e30f : bv[0];
        o.y = m.y ? -1e30f : bv[1];
        o.z = m.z ? -1e30f : bv[2];
        o.w = m.w ? -1e30f : bv[3];
        ((float4*)term)[i] = o;
    }
}

// ---------------------------------------------------------------------------
// bf16 MFMA NT GEMM, 128xBCOL tile, BK=32, 4 waves.
// MODE 0: f32 out += bias[col].
// MODE 1: bf16 out += bias[col]; cols<D scaled by SCALE_Q (q), else plain (k).
// MODE 2: rows = v-dims, cols = tokens; f16 out to V^T layout
//         [(tok>>11)*1024 + row][tok&2047]; bias per ROW; trust gate per col.
// ---------------------------------------------------------------------------
template<int BCOL, int MODE>
__global__ __launch_bounds__(256) void gemm_bt(
    const ushort* __restrict__ A, const ushort* __restrict__ Bw,
    const float* __restrict__ bias, float* __restrict__ Cf,
    ushort* __restrict__ Ch, int Ncol, int K,
    const float* __restrict__ ctx_trust, const float* __restrict__ trust_scale,
    const int* __restrict__ n_ctx_p)
{
    constexpr int NT = BCOL / 32;
    __shared__ ushort tA[128 * 32];
    __shared__ ushort tB[BCOL * 32];
    const int tid = threadIdx.x;
    const int lane = tid & 63, wv = tid >> 6;
    const int ln = lane & 15, kg = lane >> 4;
    const int rh = wv >> 1, ch = wv & 1;
    const int row0 = blockIdx.y * 128, col0 = blockIdx.x * BCOL;

    int offA[4], offB[NT];
    #pragma unroll
    for (int i = 0; i < 4; ++i) {
        int ra = rh * 64 + i * 16 + ln;
        offA[i] = ra * 32 + ((kg ^ ((ra >> 1) & 3)) << 3);
    }
    #pragma unroll
    for (int i = 0; i < NT; ++i) {
        int rb = ch * (BCOL / 2) + i * 16 + ln;
        offB[i] = rb * 32 + ((kg ^ ((rb >> 1) & 3)) << 3);
    }
    f32x4 acc[4][NT];
    #pragma unroll
    for (int i = 0; i < 4; ++i)
        #pragma unroll
        for (int j = 0; j < NT; ++j) acc[i][j] = (f32x4){0.f, 0.f, 0.f, 0.f};

    for (int kt = 0; kt < K; kt += 32) {
        __syncthreads();
        #pragma unroll
        for (int r2 = 0; r2 < 2; ++r2) {
            int g = r2 * 256 + tid;
            int row = g >> 2;
            int srck = ((g & 3) ^ ((row >> 1) & 3)) << 3;
            async16(A + (size_t)(row0 + row) * K + kt + srck, &tA[g * 8]);
        }
        #pragma unroll
        for (int r2 = 0; r2 < BCOL / 64; ++r2) {
            int g = r2 * 256 + tid;
            int row = g >> 2;
            int srck = ((g & 3) ^ ((row >> 1) & 3)) << 3;
            async16(Bw + (size_t)(col0 + row) * K + kt + srck, &tB[g * 8]);
        }
        __syncthreads();
        bf16x8 af[4], bfr[NT];
        #pragma unroll
        for (int i = 0; i < 4; ++i)  af[i]  = *(const bf16x8*)&tA[offA[i]];
        #pragma unroll
        for (int i = 0; i < NT; ++i) bfr[i] = *(const bf16x8*)&tB[offB[i]];
        #pragma unroll
        for (int mt = 0; mt < 4; ++mt)
            #pragma unroll
            for (int nt = 0; nt < NT; ++nt)
                acc[mt][nt] = MFMA16(af[mt], bfr[nt], acc[mt][nt]);
    }

    const int nctx = n_ctx_p ? n_ctx_p[0] : 0;
    const float ts = trust_scale ? trust_scale[0] : 0.f;
    #pragma unroll
    for (int nt = 0; nt < NT; ++nt) {
        int col = col0 + ch * (BCOL / 2) + nt * 16 + ln;
        float cbv = (MODE != 2) ? bias[col] : 0.f;
        float gmul = 1.f;
        if (MODE == 2) {
            int tok = col & (N_ - 1);
            if (tok < nctx)
                gmul = 1.f / (1.f + __expf(-ts * ctx_trust[tok]));
        }
        #pragma unroll
        for (int mt = 0; mt < 4; ++mt) {
            int rbase = row0 + rh * 64 + mt * 16 + kg * 4;
            f32x4 a = acc[mt][nt];
            if (MODE == 0) {
                #pragma unroll
                for (int reg = 0; reg < 4; ++reg)
                    Cf[(size_t)(rbase + reg) * Ncol + col] = a[reg] + cbv;
            } else if (MODE == 1) {
                const float qs = (col < D_) ? SCALE_Q : 1.f;
                #pragma unroll
                for (int reg = 0; reg < 4; ++reg)
                    Ch[(size_t)(rbase + reg) * Ncol + col] = f2bf((a[reg] + cbv) * qs);
            } else {
                f32x4 bv4 = *(const f32x4*)&bias[rbase];
                #pragma unroll
                for (int reg = 0; reg < 4; ++reg) {
                    float v = (a[reg] + bv4[reg]) * gmul;
                    _Float16 hv = (_Float16)v;
                    union { _Float16 h; ushort u; } cv; cv.h = hv;
                    Ch[((size_t)((col >> 11) * 1024 + rbase + reg)) * 2048 + (col & (N_ - 1))] = cv.u;
                }
            }
        }
    }
}

// ---------------------------------------------------------------------------
// Flash attention, 32x32 MFMA, max-less log2-domain softmax, fused term table.
// Block = 8 waves x 32 q = 256 q of one (b,h), 512 threads. One shared K/V
// double-buffer -> 32 KB LDS, grid 256 = 1 block/CU, 16 waves/CU (4/SIMD).
// ---------------------------------------------------------------------------
__global__ __launch_bounds__(512, 4) void attn(
    const ushort* __restrict__ qkb,      // [4096][2048] bf16: q | k
    const _Float16* __restrict__ vT,     // [2*1024][2048] f16 (b*1024+h*64+dim) x token
    const float* __restrict__ term,      // [2048][2048] f32 fused mask+bias-4
    ushort* __restrict__ attb)           // [4096][1024] bf16
{
    __shared__ ushort   Kt[2][64 * 64];
    __shared__ _Float16 Vt[2][64 * 64];
    const int tid = threadIdx.x;
    const int lane = tid & 63, wv = tid >> 6;      // wv in [0,8)
    const int q31 = lane & 31, hi = lane >> 5;
    const int bh = blockIdx.x;
    const int b = bh >> 4, h = bh & 15;
    const int q = blockIdx.y * 256 + wv * 32 + q31;   // this lane's query row

    bf16x8 qf[4];
    {
        const ushort* qrow = qkb + (size_t)(b * N_ + q) * 2048 + h * 64;
        #pragma unroll
        for (int ks = 0; ks < 4; ++ks)
            qf[ks] = *(const bf16x8*)(qrow + ks * 16 + hi * 8);
    }
    const size_t kgbase = (size_t)(b * N_) * 2048 + 1024 + h * 64;
    const _Float16* vbase = vT + (size_t)(b * 1024 + h * 64) * 2048;
    const float* trow = term + (size_t)q * 2048;

    f32x16 O[2];
    O[0] = (f32x16)(0.f); O[1] = (f32x16)(0.f);
    float lrun = 0.f;

    // stage chunk 0: 512 K-granules + 512 V-granules, one each per thread
    {
        int g = tid; int row = g >> 3;
        int sg = (g & 7) ^ ((row ^ (row >> 3)) & 7);
        async16(qkb + kgbase + (size_t)row * 2048 + sg * 8, &Kt[0][g * 8]);
        async16(vbase + (size_t)row * 2048 + sg * 8, &Vt[0][g * 8]);
    }

    int fsw[2];
    #pragma unroll
    for (int t = 0; t < 2; ++t) {
        int row = t * 32 + q31;
        fsw[t] = (row ^ (row >> 3)) & 7;
    }

    for (int ci = 0; ci < 32; ++ci) {
        const int c0 = ci * 64;
        __syncthreads();
        if (ci < 31) {
            const int c1 = c0 + 64, nb = (ci + 1) & 1;
            int g = tid; int row = g >> 3;
            int sg = (g & 7) ^ ((row ^ (row >> 3)) & 7);
            async16(qkb + kgbase + (size_t)(c1 + row) * 2048 + sg * 8, &Kt[nb][g * 8]);
            async16(vbase + (size_t)row * 2048 + c1 + sg * 8, &Vt[nb][g * 8]);
        }
        const ushort*   KT = Kt[ci & 1];
        const _Float16* VT = Vt[ci & 1];

        // term loads (independent of MFMA — scheduler hoists)
        f32x4 tm[2][4];
        #pragma unroll
        for (int t = 0; t < 2; ++t)
            #pragma unroll
            for (int g = 0; g < 4; ++g)
                tm[t][g] = *(const f32x4*)(trow + c0 + t * 32 + g * 8 + hi * 4);

        // ---- S^T = K · Q^T ----
        f32x16 S[2];
        S[0] = (f32x16)(0.f); S[1] = (f32x16)(0.f);
        #pragma unroll
        for (int t = 0; t < 2; ++t) {
            const int rbase = (t * 32 + q31) * 64;
            #pragma unroll
            for (int ks = 0; ks < 4; ++ks) {
                bf16x8 kf = *(const bf16x8*)&KT[rbase + (((ks * 2 + hi) ^ fsw[t]) << 3)];
                S[t] = MFMA32B(kf, qf[ks], S[t]);
            }
        }

        // ---- softmax: p = exp2(S + term); lsum via packed-f16 tree ----
        unsigned pk[2][8];
        __half2 hs0 = __float2half2_rn(0.f), hs1 = __float2half2_rn(0.f);
        #pragma unroll
        for (int t = 0; t < 2; ++t) {
            float p[16];
            #pragma unroll
            for (int g = 0; g < 4; ++g)
                #pragma unroll
                for (int r = 0; r < 4; ++r) {
                    const int reg = g * 4 + r;
                    p[reg] = __builtin_exp2f(S[t][reg] + tm[t][g][r]);
                }
            #pragma unroll
            for (int i = 0; i < 8; ++i) {
                pk[t][i] = pkrtz(p[2 * i], p[2 * i + 1]);
                union { unsigned u; __half2 h; } c; c.u = pk[t][i];
                if (i & 1) hs1 = __hadd2(hs1, c.h); else hs0 = __hadd2(hs0, c.h);
            }
        }
        {
            __half2 hs = __hadd2(hs0, hs1);
            lrun += __low2float(hs) + __high2float(hs);
        }

        // ---- PV: out^T += V^T · P^T ----
        #pragma unroll
        for (int ks = 0; ks < 4; ++ks) {
            const int t = ks >> 1, lo4 = (ks & 1) * 4;
            unsigned u0 = pk[t][lo4 + 0], u1 = pk[t][lo4 + 1];
            unsigned u2 = pk[t][lo4 + 2], u3 = pk[t][lo4 + 3];
            unsigned own0 = hi ? u2 : u0, own1 = hi ? u3 : u1;
            unsigned snd0 = hi ? u0 : u2, snd1 = hi ? u1 : u3;
            unsigned rv0 = (unsigned)__shfl_xor((int)snd0, 32);
            unsigned rv1 = (unsigned)__shfl_xor((int)snd1, 32);
            union { f16x8 v; unsigned u[4]; } frag;
            frag.u[0] = hi ? rv0 : own0;
            frag.u[1] = hi ? rv1 : own1;
            frag.u[2] = hi ? own0 : rv0;
            frag.u[3] = hi ? own1 : rv1;
            #pragma unroll
            for (int t2 = 0; t2 < 2; ++t2) {
                const int vb = (t2 * 32 + q31) * 64;
                union { f16x8 v; int4 i; } vf;
                vf.i = *(const int4*)&VT[vb + (((ks * 2 + hi) ^ fsw[t2]) << 3)];
                O[t2] = MFMA32H(vf.v, frag.v, O[t2]);
            }
        }
    }

    // ---- epilogue ----
    float l = lrun + __shfl_xor(lrun, 32);
    float inv = 1.f / l;
    ushort* orow = attb + (size_t)(b * N_ + q) * 1024 + h * 64;
    #pragma unroll
    for (int t = 0; t < 2; ++t)
        #pragma unroll
        for (int g = 0; g < 4; ++g) {
            ushort4 o;
            #pragma unroll
            for (int r = 0; r < 4; ++r)
                ((ushort*)&o)[r] = f2bf(O[t][g * 4 + r] * inv);
            *(ushort4*)&orow[t * 32 + g * 8 + hi * 4] = o;
        }
}

extern "C" void kernel_launch(void* const* d_in, const int* in_sizes, int n_in,
                              void* d_out, int out_size, void* d_ws, size_t ws_size,
                              hipStream_t stream)
{
    const float* x         = (const float*)d_in[0];
    const float* ctx_ppr   = (const float*)d_in[1];
    const float* ctx_trust = (const float*)d_in[2];
    const int*   n_ctx_p   = (const int*)d_in[3];
    const int*   attn_mask = (const int*)d_in[4];
    const float* W_in      = (const float*)d_in[5];
    const float* b_in      = (const float*)d_in[6];
    const float* W_out     = (const float*)d_in[7];
    const float* b_out     = (const float*)d_in[8];
    const float* log_alpha = (const float*)d_in[9];
    const float* trust_sc  = (const float*)d_in[10];
    float* out = (float*)d_out;

    char* ws = (char*)d_ws;
    ushort*    xb     = (ushort*)ws;    ws += (size_t)4096 * 1024 * 2;   // 8 MB
    ushort*    wib    = (ushort*)ws;    ws += (size_t)3072 * 1024 * 2;   // 6 MB
    ushort*    wob    = (ushort*)ws;    ws += (size_t)1024 * 1024 * 2;   // 2 MB
    ushort*    qkb    = (ushort*)ws;    ws += (size_t)4096 * 2048 * 2;   // 16 MB
    _Float16*  vT     = (_Float16*)ws;  ws += (size_t)2048 * 2048 * 2;   // 8 MB
    ushort*    attbuf = (ushort*)ws;    ws += (size_t)4096 * 1024 * 2;   // 8 MB
    float*     term   = (float*)ws;     ws += (size_t)2048 * 2048 * 4;   // 16 MB

    hipLaunchKernelGGL(preprocess, dim3(12288), dim3(256), 0, stream,
                       x, W_in, W_out, ctx_ppr, log_alpha, n_ctx_p, attn_mask,
                       xb, wib, wob, term);

    // qk = x @ W_qk^T (+b), q pre-scaled               [4096 tok][2048]
    hipLaunchKernelGGL((gemm_bt<128, 1>), dim3(16, 32), dim3(256), 0, stream,
                       xb, wib, b_in, (float*)nullptr, qkb, 2048, 1024,
                       (const float*)nullptr, (const float*)nullptr, (const int*)nullptr);

    // V^T = Wv @ x^T (+bv per row), trust-gated per token  [2*1024 dims][2048 tok]
    hipLaunchKernelGGL((gemm_bt<64, 2>), dim3(64, 8), dim3(256), 0, stream,
                       wib + (size_t)2048 * 1024, xb, b_in + 2 * D_, (float*)nullptr,
                       (ushort*)vT, 4096, 1024, ctx_trust, trust_sc, n_ctx_p);

    hipLaunchKernelGGL(attn, dim3(32, 8), dim3(512), 0, stream,
                       qkb, vT, term, attbuf);

    hipLaunchKernelGGL((gemm_bt<64, 0>), dim3(16, 32), dim3(256), 0, stream,
                       attbuf, wob, b_out, out, (ushort*)nullptr, 1024, 1024,
                       (const float*)nullptr, (const float*)nullptr, (const int*)nullptr);
}

// Round 7
// 269.100 us; speedup vs baseline: 1.0797x; 1.0797x over previous
//
#include <hip/hip_runtime.h>
#include <hip/hip_bf16.h>
#include <hip/hip_fp16.h>
#include <math.h>

#define B_   2
#define N_   2048
#define D_   1024
#define H_   16
#define TD_  3072
#define LOG2E 1.44269504088896340736f
#define SCALE_Q (0.125f * LOG2E)

typedef short  bf16x8 __attribute__((ext_vector_type(8)));
typedef _Float16 f16x8 __attribute__((ext_vector_type(8)));
typedef float  f32x4  __attribute__((ext_vector_type(4)));
typedef float  f32x16 __attribute__((ext_vector_type(16)));

#define MFMA16(a, b, c)   __builtin_amdgcn_mfma_f32_16x16x32_bf16(a, b, c, 0, 0, 0)
#define MFMA32B(a, b, c)  __builtin_amdgcn_mfma_f32_32x32x16_bf16(a, b, c, 0, 0, 0)
#define MFMA32H(a, b, c)  __builtin_amdgcn_mfma_f32_32x32x16_f16(a, b, c, 0, 0, 0)

__device__ __forceinline__ ushort f2bf(float f) {
    union { float f; unsigned u; } v; v.f = f;
    unsigned r = (v.u + 0x7fffu + ((v.u >> 16) & 1u)) >> 16;
    return (ushort)r;
}
__device__ __forceinline__ unsigned pkrtz(float a, float b) {
    typedef __fp16 h2 __attribute__((ext_vector_type(2)));
    union { h2 h; unsigned u; } c;
    c.h = __builtin_amdgcn_cvt_pkrtz(a, b);
    return c.u;
}
__device__ __forceinline__ void async16(const void* g, void* l) {
    __builtin_amdgcn_global_load_lds(
        (const __attribute__((address_space(1))) unsigned*)g,
        (__attribute__((address_space(3))) unsigned*)l, 16, 0, 0);
}

// ---------------------------------------------------------------------------
// Preprocess: bf16 casts of x/W_in/W_out; fused term table
// term[q][k] = mask ? -1e30 : (k<nctx ? alpha*log2(ppr_k) - 4 : -4)   (f32)
// ---------------------------------------------------------------------------
__global__ __launch_bounds__(256) void preprocess(
    const float* __restrict__ x, const float* __restrict__ W_in,
    const float* __restrict__ W_out, const float* __restrict__ ctx_ppr,
    const float* __restrict__ log_alpha, const int* __restrict__ n_ctx_p,
    const int* __restrict__ mask,
    ushort* __restrict__ xb, ushort* __restrict__ wib, ushort* __restrict__ wob,
    float* __restrict__ term)
{
    const int J0 = 1048576, J1 = 786432, J2 = 262144, JT = 1048576;
    int t = blockIdx.x * 256 + threadIdx.x;
    if (t < J0 + J1 + J2) {
        const float* src; ushort* dst; int i = t;
        if (i < J0)           { src = x;      dst = xb;  }
        else if (i < J0 + J1) { i -= J0;      src = W_in;  dst = wib; }
        else                  { i -= J0 + J1; src = W_out; dst = wob; }
        float4 v = ((const float4*)src)[i];
        ushort4 o;
        o.x = f2bf(v.x); o.y = f2bf(v.y); o.z = f2bf(v.z); o.w = f2bf(v.w);
        ((ushort4*)dst)[i] = o;
    } else if (t < J0 + J1 + J2 + JT) {
        int i = t - (J0 + J1 + J2);          // one float4 of term, int4 of mask
        int k4 = (i & 511) * 4;
        int4 m = ((const int4*)mask)[i];
        int nc = n_ctx_p[0];
        float al = log_alpha[0];
        float4 o;
        float bv[4];
        #pragma unroll
        for (int j = 0; j < 4; ++j) {
            int k = k4 + j;
            bv[j] = (k < nc) ? (al * __log2f(fmaxf(ctx_ppr[k], 1e-8f)) - 4.f) : -4.f;
        }
        o.x = m.x ? -1e30f : bv[0];
        o.y = m.y ? -1e30f : bv[1];
        o.z = m.z ? -1e30f : bv[2];
        o.w = m.w ? -1e30f : bv[3];
        ((float4*)term)[i] = o;
    }
}

// ---------------------------------------------------------------------------
// bf16 MFMA NT GEMM, 128xBCOL tile, BK=32, 4 waves.
// MODE 0: f32 out += bias[col].
// MODE 1: bf16 out += bias[col]; cols<D scaled by SCALE_Q (q), else plain (k).
// MODE 2: rows = v-dims, cols = tokens; f16 out to V^T layout
//         [(tok>>11)*1024 + row][tok&2047]; bias per ROW; trust gate per col.
// ---------------------------------------------------------------------------
template<int BCOL, int MODE>
__global__ __launch_bounds__(256) void gemm_bt(
    const ushort* __restrict__ A, const ushort* __restrict__ Bw,
    const float* __restrict__ bias, float* __restrict__ Cf,
    ushort* __restrict__ Ch, int Ncol, int K,
    const float* __restrict__ ctx_trust, const float* __restrict__ trust_scale,
    const int* __restrict__ n_ctx_p)
{
    constexpr int NT = BCOL / 32;
    __shared__ ushort tA[128 * 32];
    __shared__ ushort tB[BCOL * 32];
    const int tid = threadIdx.x;
    const int lane = tid & 63, wv = tid >> 6;
    const int ln = lane & 15, kg = lane >> 4;
    const int rh = wv >> 1, ch = wv & 1;
    const int row0 = blockIdx.y * 128, col0 = blockIdx.x * BCOL;

    int offA[4], offB[NT];
    #pragma unroll
    for (int i = 0; i < 4; ++i) {
        int ra = rh * 64 + i * 16 + ln;
        offA[i] = ra * 32 + ((kg ^ ((ra >> 1) & 3)) << 3);
    }
    #pragma unroll
    for (int i = 0; i < NT; ++i) {
        int rb = ch * (BCOL / 2) + i * 16 + ln;
        offB[i] = rb * 32 + ((kg ^ ((rb >> 1) & 3)) << 3);
    }
    f32x4 acc[4][NT];
    #pragma unroll
    for (int i = 0; i < 4; ++i)
        #pragma unroll
        for (int j = 0; j < NT; ++j) acc[i][j] = (f32x4){0.f, 0.f, 0.f, 0.f};

    for (int kt = 0; kt < K; kt += 32) {
        __syncthreads();
        #pragma unroll
        for (int r2 = 0; r2 < 2; ++r2) {
            int g = r2 * 256 + tid;
            int row = g >> 2;
            int srck = ((g & 3) ^ ((row >> 1) & 3)) << 3;
            async16(A + (size_t)(row0 + row) * K + kt + srck, &tA[g * 8]);
        }
        #pragma unroll
        for (int r2 = 0; r2 < BCOL / 64; ++r2) {
            int g = r2 * 256 + tid;
            int row = g >> 2;
            int srck = ((g & 3) ^ ((row >> 1) & 3)) << 3;
            async16(Bw + (size_t)(col0 + row) * K + kt + srck, &tB[g * 8]);
        }
        __syncthreads();
        bf16x8 af[4], bfr[NT];
        #pragma unroll
        for (int i = 0; i < 4; ++i)  af[i]  = *(const bf16x8*)&tA[offA[i]];
        #pragma unroll
        for (int i = 0; i < NT; ++i) bfr[i] = *(const bf16x8*)&tB[offB[i]];
        #pragma unroll
        for (int mt = 0; mt < 4; ++mt)
            #pragma unroll
            for (int nt = 0; nt < NT; ++nt)
                acc[mt][nt] = MFMA16(af[mt], bfr[nt], acc[mt][nt]);
    }

    const int nctx = n_ctx_p ? n_ctx_p[0] : 0;
    const float ts = trust_scale ? trust_scale[0] : 0.f;
    #pragma unroll
    for (int nt = 0; nt < NT; ++nt) {
        int col = col0 + ch * (BCOL / 2) + nt * 16 + ln;
        float cbv = (MODE != 2) ? bias[col] : 0.f;
        float gmul = 1.f;
        if (MODE == 2) {
            int tok = col & (N_ - 1);
            if (tok < nctx)
                gmul = 1.f / (1.f + __expf(-ts * ctx_trust[tok]));
        }
        #pragma unroll
        for (int mt = 0; mt < 4; ++mt) {
            int rbase = row0 + rh * 64 + mt * 16 + kg * 4;
            f32x4 a = acc[mt][nt];
            if (MODE == 0) {
                #pragma unroll
                for (int reg = 0; reg < 4; ++reg)
                    Cf[(size_t)(rbase + reg) * Ncol + col] = a[reg] + cbv;
            } else if (MODE == 1) {
                const float qs = (col < D_) ? SCALE_Q : 1.f;
                #pragma unroll
                for (int reg = 0; reg < 4; ++reg)
                    Ch[(size_t)(rbase + reg) * Ncol + col] = f2bf((a[reg] + cbv) * qs);
            } else {
                f32x4 bv4 = *(const f32x4*)&bias[rbase];
                #pragma unroll
                for (int reg = 0; reg < 4; ++reg) {
                    float v = (a[reg] + bv4[reg]) * gmul;
                    _Float16 hv = (_Float16)v;
                    union { _Float16 h; ushort u; } cv; cv.h = hv;
                    Ch[((size_t)((col >> 11) * 1024 + rbase + reg)) * 2048 + (col & (N_ - 1))] = cv.u;
                }
            }
        }
    }
}

// ---------------------------------------------------------------------------
// Split-K flash attention, 32x32 MFMA, max-less log2-domain softmax.
// Max-less softmax => partials are exactly additive: O = sum_z O_z, l = sum_z l_z.
// Grid (bh=32, qb=8, z=2): 512 blocks x 8 waves = 16 waves/CU = 4/SIMD.
// Each block: 256 q of one (b,h), keys [z*1024, z*1024+1024), 16 chunks of 64.
// Writes unnormalized f32 partial O and partial l to workspace.
// ---------------------------------------------------------------------------
__global__ __launch_bounds__(512, 4) void attn(
    const ushort* __restrict__ qkb,      // [4096][2048] bf16: q | k
    const _Float16* __restrict__ vT,     // [2*1024][2048] f16 (b*1024+h*64+dim) x token
    const float* __restrict__ term,      // [2048][2048] f32 fused mask+bias-4
    float* __restrict__ pO,              // [2][32][2048][64] f32 partial O
    float* __restrict__ pl)              // [2][32][2048]     f32 partial l
{
    __shared__ ushort   Kt[2][64 * 64];
    __shared__ _Float16 Vt[2][64 * 64];
    const int tid = threadIdx.x;
    const int lane = tid & 63, wv = tid >> 6;      // wv in [0,8)
    const int q31 = lane & 31, hi = lane >> 5;
    const int bh = blockIdx.x;
    const int b = bh >> 4, h = bh & 15;
    const int z = blockIdx.z;
    const int k0z = z * 1024;                       // key range base
    const int q = blockIdx.y * 256 + wv * 32 + q31; // this lane's query row

    bf16x8 qf[4];
    {
        const ushort* qrow = qkb + (size_t)(b * N_ + q) * 2048 + h * 64;
        #pragma unroll
        for (int ks = 0; ks < 4; ++ks)
            qf[ks] = *(const bf16x8*)(qrow + ks * 16 + hi * 8);
    }
    const size_t kgbase = (size_t)(b * N_) * 2048 + 1024 + h * 64;
    const _Float16* vbase = vT + (size_t)(b * 1024 + h * 64) * 2048;
    const float* trow = term + (size_t)q * 2048 + k0z;

    f32x16 O[2];
    O[0] = (f32x16)(0.f); O[1] = (f32x16)(0.f);
    float lrun = 0.f;

    // stage chunk 0: 512 K-granules + 512 V-granules, one each per thread
    {
        int g = tid; int row = g >> 3;
        int sg = (g & 7) ^ ((row ^ (row >> 3)) & 7);
        async16(qkb + kgbase + (size_t)(k0z + row) * 2048 + sg * 8, &Kt[0][g * 8]);
        async16(vbase + (size_t)row * 2048 + k0z + sg * 8, &Vt[0][g * 8]);
    }

    int fsw[2];
    #pragma unroll
    for (int t = 0; t < 2; ++t) {
        int row = t * 32 + q31;
        fsw[t] = (row ^ (row >> 3)) & 7;
    }

    for (int ci = 0; ci < 16; ++ci) {
        const int c0 = ci * 64;
        __syncthreads();
        if (ci < 15) {
            const int c1 = c0 + 64, nb = (ci + 1) & 1;
            int g = tid; int row = g >> 3;
            int sg = (g & 7) ^ ((row ^ (row >> 3)) & 7);
            async16(qkb + kgbase + (size_t)(k0z + c1 + row) * 2048 + sg * 8, &Kt[nb][g * 8]);
            async16(vbase + (size_t)row * 2048 + k0z + c1 + sg * 8, &Vt[nb][g * 8]);
        }
        const ushort*   KT = Kt[ci & 1];
        const _Float16* VT = Vt[ci & 1];

        // term loads (independent of MFMA — scheduler hoists)
        f32x4 tm[2][4];
        #pragma unroll
        for (int t = 0; t < 2; ++t)
            #pragma unroll
            for (int g = 0; g < 4; ++g)
                tm[t][g] = *(const f32x4*)(trow + c0 + t * 32 + g * 8 + hi * 4);

        // ---- S^T = K · Q^T ----
        f32x16 S[2];
        S[0] = (f32x16)(0.f); S[1] = (f32x16)(0.f);
        #pragma unroll
        for (int t = 0; t < 2; ++t) {
            const int rbase = (t * 32 + q31) * 64;
            #pragma unroll
            for (int ks = 0; ks < 4; ++ks) {
                bf16x8 kf = *(const bf16x8*)&KT[rbase + (((ks * 2 + hi) ^ fsw[t]) << 3)];
                S[t] = MFMA32B(kf, qf[ks], S[t]);
            }
        }

        // ---- softmax: p = exp2(S + term); lsum via packed-f16 tree ----
        unsigned pk[2][8];
        __half2 hs0 = __float2half2_rn(0.f), hs1 = __float2half2_rn(0.f);
        #pragma unroll
        for (int t = 0; t < 2; ++t) {
            float p[16];
            #pragma unroll
            for (int g = 0; g < 4; ++g)
                #pragma unroll
                for (int r = 0; r < 4; ++r) {
                    const int reg = g * 4 + r;
                    p[reg] = __builtin_exp2f(S[t][reg] + tm[t][g][r]);
                }
            #pragma unroll
            for (int i = 0; i < 8; ++i) {
                pk[t][i] = pkrtz(p[2 * i], p[2 * i + 1]);
                union { unsigned u; __half2 h; } c; c.u = pk[t][i];
                if (i & 1) hs1 = __hadd2(hs1, c.h); else hs0 = __hadd2(hs0, c.h);
            }
        }
        {
            __half2 hs = __hadd2(hs0, hs1);
            lrun += __low2float(hs) + __high2float(hs);
        }

        // ---- PV: out^T += V^T · P^T ----
        #pragma unroll
        for (int ks = 0; ks < 4; ++ks) {
            const int t = ks >> 1, lo4 = (ks & 1) * 4;
            unsigned u0 = pk[t][lo4 + 0], u1 = pk[t][lo4 + 1];
            unsigned u2 = pk[t][lo4 + 2], u3 = pk[t][lo4 + 3];
            unsigned own0 = hi ? u2 : u0, own1 = hi ? u3 : u1;
            unsigned snd0 = hi ? u0 : u2, snd1 = hi ? u1 : u3;
            unsigned rv0 = (unsigned)__shfl_xor((int)snd0, 32);
            unsigned rv1 = (unsigned)__shfl_xor((int)snd1, 32);
            union { f16x8 v; unsigned u[4]; } frag;
            frag.u[0] = hi ? rv0 : own0;
            frag.u[1] = hi ? rv1 : own1;
            frag.u[2] = hi ? own0 : rv0;
            frag.u[3] = hi ? own1 : rv1;
            #pragma unroll
            for (int t2 = 0; t2 < 2; ++t2) {
                const int vb = (t2 * 32 + q31) * 64;
                union { f16x8 v; int4 i; } vf;
                vf.i = *(const int4*)&VT[vb + (((ks * 2 + hi) ^ fsw[t2]) << 3)];
                O[t2] = MFMA32H(vf.v, frag.v, O[t2]);
            }
        }
    }

    // ---- epilogue: store unnormalized partial O (f32) and partial l ----
    float* obase = pO + (((size_t)(z * 32 + bh) * 2048) + q) * 64;
    #pragma unroll
    for (int t = 0; t < 2; ++t)
        #pragma unroll
        for (int g = 0; g < 4; ++g) {
            f32x4 o4 = { O[t][g * 4 + 0], O[t][g * 4 + 1], O[t][g * 4 + 2], O[t][g * 4 + 3] };
            *(f32x4*)(obase + t * 32 + g * 8 + hi * 4) = o4;
        }
    float l = lrun + __shfl_xor(lrun, 32);
    if (hi == 0)
        pl[(size_t)(z * 32 + bh) * 2048 + q] = l;
}

// ---------------------------------------------------------------------------
// Combine: attb = bf16( (pO_0 + pO_1) / (pl_0 + pl_1) )
// ---------------------------------------------------------------------------
__global__ __launch_bounds__(256) void combine(
    const float* __restrict__ pO, const float* __restrict__ pl,
    ushort* __restrict__ attb)
{
    int i = blockIdx.x * 256 + threadIdx.x;        // [0, 32*2048*16)
    int bhq = i >> 4, d4 = (i & 15) << 2;
    const float* o0 = pO + (size_t)bhq * 64 + d4;
    const float* o1 = o0 + (size_t)32 * 2048 * 64;
    float l = pl[bhq] + pl[bhq + 32 * 2048];
    float inv = 1.f / l;
    f32x4 a = *(const f32x4*)o0;
    f32x4 b = *(const f32x4*)o1;
    ushort4 o;
    #pragma unroll
    for (int r = 0; r < 4; ++r)
        ((ushort*)&o)[r] = f2bf((a[r] + b[r]) * inv);
    int bh = bhq >> 11, q = bhq & 2047;
    *(ushort4*)&attb[((size_t)((bh >> 4) * 2048 + q)) * 1024 + (bh & 15) * 64 + d4] = o;
}

extern "C" void kernel_launch(void* const* d_in, const int* in_sizes, int n_in,
                              void* d_out, int out_size, void* d_ws, size_t ws_size,
                              hipStream_t stream)
{
    const float* x         = (const float*)d_in[0];
    const float* ctx_ppr   = (const float*)d_in[1];
    const float* ctx_trust = (const float*)d_in[2];
    const int*   n_ctx_p   = (const int*)d_in[3];
    const int*   attn_mask = (const int*)d_in[4];
    const float* W_in      = (const float*)d_in[5];
    const float* b_in      = (const float*)d_in[6];
    const float* W_out     = (const float*)d_in[7];
    const float* b_out     = (const float*)d_in[8];
    const float* log_alpha = (const float*)d_in[9];
    const float* trust_sc  = (const float*)d_in[10];
    float* out = (float*)d_out;

    char* ws = (char*)d_ws;
    ushort*    xb     = (ushort*)ws;    ws += (size_t)4096 * 1024 * 2;   // 8 MB
    ushort*    wib    = (ushort*)ws;    ws += (size_t)3072 * 1024 * 2;   // 6 MB
    ushort*    wob    = (ushort*)ws;    ws += (size_t)1024 * 1024 * 2;   // 2 MB
    ushort*    qkb    = (ushort*)ws;    ws += (size_t)4096 * 2048 * 2;   // 16 MB
    _Float16*  vT     = (_Float16*)ws;  ws += (size_t)2048 * 2048 * 2;   // 8 MB
    ushort*    attbuf = (ushort*)ws;    ws += (size_t)4096 * 1024 * 2;   // 8 MB
    float*     term   = (float*)ws;     ws += (size_t)2048 * 2048 * 4;   // 16 MB
    float*     pO     = (float*)ws;     ws += (size_t)2 * 32 * 2048 * 64 * 4; // 32 MB
    float*     pl     = (float*)ws;     ws += (size_t)2 * 32 * 2048 * 4;      // 512 KB

    hipLaunchKernelGGL(preprocess, dim3(12288), dim3(256), 0, stream,
                       x, W_in, W_out, ctx_ppr, log_alpha, n_ctx_p, attn_mask,
                       xb, wib, wob, term);

    // qk = x @ W_qk^T (+b), q pre-scaled               [4096 tok][2048]
    hipLaunchKernelGGL((gemm_bt<128, 1>), dim3(16, 32), dim3(256), 0, stream,
                       xb, wib, b_in, (float*)nullptr, qkb, 2048, 1024,
                       (const float*)nullptr, (const float*)nullptr, (const int*)nullptr);

    // V^T = Wv @ x^T (+bv per row), trust-gated per token  [2*1024 dims][2048 tok]
    hipLaunchKernelGGL((gemm_bt<64, 2>), dim3(64, 8), dim3(256), 0, stream,
                       wib + (size_t)2048 * 1024, xb, b_in + 2 * D_, (float*)nullptr,
                       (ushort*)vT, 4096, 1024, ctx_trust, trust_sc, n_ctx_p);

    // split-K attention: z in {0,1}
    hipLaunchKernelGGL(attn, dim3(32, 8, 2), dim3(512), 0, stream,
                       qkb, vT, term, pO, pl);

    hipLaunchKernelGGL(combine, dim3(4096), dim3(256), 0, stream,
                       pO, pl, attbuf);

    hipLaunchKernelGGL((gemm_bt<64, 0>), dim3(16, 32), dim3(256), 0, stream,
                       attbuf, wob, b_out, out, (ushort*)nullptr, 1024, 1024,
                       (const float*)nullptr, (const float*)nullptr, (const int*)nullptr);
}